// Round 1
// baseline (480.062 us; speedup 1.0000x reference)
//
#include <hip/hip_runtime.h>
#include <hip/hip_bf16.h>
#include <stdint.h>

#define N 8192
#define K 64
#define TILE 128
#define LSTRIDE 72   // bf16 elems per LDS row: 64 + 8 pad (144 B, 16B-aligned, 2-way bank alias = free)

typedef __attribute__((ext_vector_type(8))) short bf16x8;
typedef __attribute__((ext_vector_type(4))) float floatx4;

// ---------------- prep: Y fp32 -> bf16, and sq[i] = ||y_i||^2 ----------------
__global__ __launch_bounds__(256) void prep_kernel(const float* __restrict__ Y,
                                                   unsigned short* __restrict__ Ybf,
                                                   float* __restrict__ sq) {
    int row  = blockIdx.x * 4 + (threadIdx.x >> 6);   // one wave per row
    int lane = threadIdx.x & 63;                      // K == 64 == wave size
    float v = Y[row * K + lane];
    // round-to-nearest-even fp32 -> bf16
    uint32_t bits = __float_as_uint(v);
    uint32_t rnd  = bits + 0x7FFF + ((bits >> 16) & 1);
    Ybf[row * K + lane] = (unsigned short)(rnd >> 16);
    float s = v * v;
    #pragma unroll
    for (int off = 32; off > 0; off >>= 1) s += __shfl_down(s, off, 64);
    if (lane == 0) sq[row] = s;
}

// ---------------- main: per 128x128 tile, G = Y Y^T via MFMA, weight by W ----
__global__ __launch_bounds__(256) void loss_kernel(const float* __restrict__ W,
                                                   const unsigned short* __restrict__ Ybf,
                                                   const float* __restrict__ sq,
                                                   float* __restrict__ out) {
    __shared__ __align__(16) short lA[TILE * LSTRIDE];
    __shared__ __align__(16) short lB[TILE * LSTRIDE];
    __shared__ float sqA[TILE];
    __shared__ float sqB[TILE];
    __shared__ float wsum[4];

    const int i0 = (blockIdx.x >> 6) * TILE;
    const int j0 = (blockIdx.x & 63) * TILE;
    const int tid = threadIdx.x;

    // Stage both Y tiles (128 rows x 128 B) into LDS, 16 B per thread per iter.
    #pragma unroll
    for (int it = 0; it < 4; ++it) {
        int r   = it * 32 + (tid >> 3);
        int seg = tid & 7;                 // 16-byte segment within the row
        const bf16x8* ga = reinterpret_cast<const bf16x8*>(Ybf + (i0 + r) * K + seg * 8);
        const bf16x8* gb = reinterpret_cast<const bf16x8*>(Ybf + (j0 + r) * K + seg * 8);
        *reinterpret_cast<bf16x8*>(&lA[r * LSTRIDE + seg * 8]) = *ga;
        *reinterpret_cast<bf16x8*>(&lB[r * LSTRIDE + seg * 8]) = *gb;
    }
    if (tid < TILE) { sqA[tid] = sq[i0 + tid]; sqB[tid] = sq[j0 + tid]; }
    __syncthreads();

    const int wv   = tid >> 6;             // wave 0..3 -> 64x64 quadrant
    const int lane = tid & 63;
    const int qRow = (wv >> 1) * 64;
    const int qCol = (wv & 1) * 64;
    const int laneM = lane & 15;           // m (or n) within 16
    const int kq    = lane >> 4;           // k-quad: holds k = kq*8 .. kq*8+7

    floatx4 acc[4][4];
    #pragma unroll
    for (int mt = 0; mt < 4; ++mt)
        #pragma unroll
        for (int nt = 0; nt < 4; ++nt) acc[mt][nt] = (floatx4){0.f, 0.f, 0.f, 0.f};

    #pragma unroll
    for (int ks = 0; ks < 2; ++ks) {       // K=64 -> two k-steps of 32
        bf16x8 a[4], b[4];
        #pragma unroll
        for (int mt = 0; mt < 4; ++mt)
            a[mt] = *reinterpret_cast<const bf16x8*>(&lA[(qRow + mt * 16 + laneM) * LSTRIDE + ks * 32 + kq * 8]);
        #pragma unroll
        for (int nt = 0; nt < 4; ++nt)
            b[nt] = *reinterpret_cast<const bf16x8*>(&lB[(qCol + nt * 16 + laneM) * LSTRIDE + ks * 32 + kq * 8]);
        #pragma unroll
        for (int mt = 0; mt < 4; ++mt)
            #pragma unroll
            for (int nt = 0; nt < 4; ++nt)
                acc[mt][nt] = __builtin_amdgcn_mfma_f32_16x16x32_bf16(a[mt], b[nt], acc[mt][nt], 0, 0, 0);
    }

    // Epilogue: d = max(sq_i + sq_j - 2g, 0); partial += W[i,j]*d
    // C/D layout (verified m89/m91): col = lane&15, row = (lane>>4)*4 + reg
    float partial = 0.f;
    const int rBase = qRow + (lane >> 4) * 4;
    #pragma unroll
    for (int mt = 0; mt < 4; ++mt) {
        #pragma unroll
        for (int nt = 0; nt < 4; ++nt) {
            const int colL = qCol + nt * 16 + laneM;
            const float sqj = sqB[colL];
            #pragma unroll
            for (int r = 0; r < 4; ++r) {
                const int rowL = rBase + mt * 16 + r;
                float d = sqA[rowL] + sqj - 2.0f * acc[mt][nt][r];
                d = fmaxf(d, 0.0f);
                const float wvv = W[(size_t)(i0 + rowL) * N + (j0 + colL)];
                partial += wvv * d;
            }
        }
    }

    // wave reduce -> block reduce -> one atomic per block (scale by 1/(2n))
    #pragma unroll
    for (int off = 32; off > 0; off >>= 1) partial += __shfl_down(partial, off, 64);
    if (lane == 0) wsum[wv] = partial;
    __syncthreads();
    if (tid == 0) {
        float tot = wsum[0] + wsum[1] + wsum[2] + wsum[3];
        atomicAdd(out, tot * (1.0f / (2.0f * (float)N)));
    }
}

extern "C" void kernel_launch(void* const* d_in, const int* in_sizes, int n_in,
                              void* d_out, int out_size, void* d_ws, size_t ws_size,
                              hipStream_t stream) {
    const float* W = (const float*)d_in[0];
    const float* Y = (const float*)d_in[1];
    float* out = (float*)d_out;

    unsigned short* Ybf = (unsigned short*)d_ws;                  // N*K*2 = 1 MiB
    float* sq = (float*)((char*)d_ws + (size_t)N * K * 2);        // N*4   = 32 KiB

    hipMemsetAsync(d_out, 0, (size_t)out_size * sizeof(float), stream);
    prep_kernel<<<N / 4, 256, 0, stream>>>(Y, Ybf, sq);
    loss_kernel<<<(N / TILE) * (N / TILE), 256, 0, stream>>>(W, Ybf, sq, out);
}

// Round 2
// 361.015 us; speedup vs baseline: 1.3298x; 1.3298x over previous
//
#include <hip/hip_runtime.h>
#include <stdint.h>

#define N 8192
#define K 64
#define TILE 128

typedef __attribute__((ext_vector_type(8))) short bf16x8;
typedef __attribute__((ext_vector_type(4))) float floatx4;
typedef __attribute__((ext_vector_type(4))) unsigned short ushort4v;

// ---- prep: Y fp32 -> bf16 (RNE), sq[i] = ||y_i||^2, zero the output ----
// 16 threads per row (K=64, float4 each); 131072 threads total.
__global__ __launch_bounds__(256) void prep_kernel(const float* __restrict__ Y,
                                                   unsigned short* __restrict__ Ybf,
                                                   float* __restrict__ sq,
                                                   float* __restrict__ out) {
    if (blockIdx.x == 0 && threadIdx.x == 0) out[0] = 0.0f;
    const int t = blockIdx.x * 256 + threadIdx.x;
    floatx4 v = *reinterpret_cast<const floatx4*>(Y + (size_t)t * 4);
    ushort4v o;
    #pragma unroll
    for (int e = 0; e < 4; ++e) {
        uint32_t bits = __float_as_uint(v[e]);
        uint32_t rnd  = bits + 0x7FFF + ((bits >> 16) & 1);   // round-to-nearest-even
        o[e] = (unsigned short)(rnd >> 16);
    }
    *reinterpret_cast<ushort4v*>(Ybf + (size_t)t * 4) = o;
    float s = v[0]*v[0] + v[1]*v[1] + v[2]*v[2] + v[3]*v[3];
    #pragma unroll
    for (int m = 8; m >= 1; m >>= 1) s += __shfl_xor(s, m, 64);  // reduce within 16-lane row group
    if ((threadIdx.x & 15) == 0) sq[t >> 4] = s;
}

// ---- main: no LDS staging. Per 128x128 tile: fragments straight from L2-hot
// Ybf, W streamed as float4 (operand-swapped MFMA puts 4 consecutive W columns
// in each accumulator quad). ----
__global__ __launch_bounds__(256) void loss_kernel(const float* __restrict__ W,
                                                   const unsigned short* __restrict__ Ybf,
                                                   const float* __restrict__ sq,
                                                   float* __restrict__ out) {
    __shared__ float wsum[4];

    const int i0   = (blockIdx.x >> 6) * TILE;
    const int j0   = (blockIdx.x & 63) * TILE;
    const int tid  = threadIdx.x;
    const int wv   = tid >> 6;
    const int lane = tid & 63;
    const int qRow = (wv >> 1) * 64;          // i-quadrant base
    const int qCol = (wv & 1) * 64;           // j-quadrant base
    const int laneM = lane & 15;
    const int kq    = lane >> 4;              // k-quad / j-reg-quad

    // --- Y fragment loads (16 x 16B, L2-hot) issued first so MFMA needn't
    //     wait on the W stream (vmcnt is in-order). ---
    bf16x8 afrag[2][4], bfrag[2][4];
    #pragma unroll
    for (int ks = 0; ks < 2; ++ks) {
        #pragma unroll
        for (int mt = 0; mt < 4; ++mt) {
            const int rowA = i0 + qRow + mt * 16 + laneM;
            afrag[ks][mt] = *reinterpret_cast<const bf16x8*>(Ybf + (size_t)rowA * K + ks * 32 + kq * 8);
            const int rowB = j0 + qCol + mt * 16 + laneM;
            bfrag[ks][mt] = *reinterpret_cast<const bf16x8*>(Ybf + (size_t)rowB * K + ks * 32 + kq * 8);
        }
    }

    // --- sq loads (tiny, L2-hot) ---
    float   sqi[4];
    floatx4 sqj[4];
    #pragma unroll
    for (int mt = 0; mt < 4; ++mt)
        sqi[mt] = sq[i0 + qRow + mt * 16 + laneM];
    #pragma unroll
    for (int nt = 0; nt < 4; ++nt)
        sqj[nt] = *reinterpret_cast<const floatx4*>(sq + j0 + qCol + nt * 16 + kq * 4);

    // --- W stream: 16 float4 per lane. Lane's quad = W[i][jb..jb+3],
    //     i = i0+qRow+mt*16+laneM (fixed per mt), jb = j0+qCol+nt*16+kq*4. ---
    floatx4 wf[4][4];
    #pragma unroll
    for (int mt = 0; mt < 4; ++mt) {
        const float* wrow = W + (size_t)(i0 + qRow + mt * 16 + laneM) * N + (j0 + qCol + kq * 4);
        #pragma unroll
        for (int nt = 0; nt < 4; ++nt)
            wf[mt][nt] = *reinterpret_cast<const floatx4*>(wrow + nt * 16);
    }

    // --- MFMA, operands swapped: D[m][n] = Yj[m] . Yi[n] so that
    //     col(lane&15) = i-local, row((lane>>4)*4+reg) = j-local. ---
    floatx4 acc[4][4];
    #pragma unroll
    for (int mt = 0; mt < 4; ++mt)
        #pragma unroll
        for (int nt = 0; nt < 4; ++nt) acc[mt][nt] = (floatx4){0.f, 0.f, 0.f, 0.f};

    #pragma unroll
    for (int ks = 0; ks < 2; ++ks)
        #pragma unroll
        for (int mt = 0; mt < 4; ++mt)
            #pragma unroll
            for (int nt = 0; nt < 4; ++nt)
                acc[mt][nt] = __builtin_amdgcn_mfma_f32_16x16x32_bf16(bfrag[ks][nt], afrag[ks][mt], acc[mt][nt], 0, 0, 0);

    // --- epilogue: d = max(sq_i + sq_j - 2g, 0); partial += W*d ---
    float p0 = 0.f, p1 = 0.f, p2 = 0.f, p3 = 0.f;
    #pragma unroll
    for (int mt = 0; mt < 4; ++mt) {
        const float si = sqi[mt];
        #pragma unroll
        for (int nt = 0; nt < 4; ++nt) {
            const floatx4 g = acc[mt][nt];
            const floatx4 w4 = wf[mt][nt];
            const floatx4 sj = sqj[nt];
            float d0 = fmaxf(si + sj[0] - 2.0f * g[0], 0.f);
            float d1 = fmaxf(si + sj[1] - 2.0f * g[1], 0.f);
            float d2 = fmaxf(si + sj[2] - 2.0f * g[2], 0.f);
            float d3 = fmaxf(si + sj[3] - 2.0f * g[3], 0.f);
            p0 = fmaf(w4[0], d0, p0);
            p1 = fmaf(w4[1], d1, p1);
            p2 = fmaf(w4[2], d2, p2);
            p3 = fmaf(w4[3], d3, p3);
        }
    }
    float partial = (p0 + p1) + (p2 + p3);

    // wave reduce -> block reduce -> one atomic per block
    #pragma unroll
    for (int m = 32; m >= 1; m >>= 1) partial += __shfl_xor(partial, m, 64);
    if (lane == 0) wsum[wv] = partial;
    __syncthreads();
    if (tid == 0) {
        float tot = (wsum[0] + wsum[1]) + (wsum[2] + wsum[3]);
        atomicAdd(out, tot * (1.0f / (2.0f * (float)N)));
    }
}

extern "C" void kernel_launch(void* const* d_in, const int* in_sizes, int n_in,
                              void* d_out, int out_size, void* d_ws, size_t ws_size,
                              hipStream_t stream) {
    const float* W = (const float*)d_in[0];
    const float* Y = (const float*)d_in[1];
    float* out = (float*)d_out;

    unsigned short* Ybf = (unsigned short*)d_ws;                  // N*K*2 = 1 MiB
    float* sq = (float*)((char*)d_ws + (size_t)N * K * 2);        // N*4   = 32 KiB

    prep_kernel<<<(N * K / 4) / 256, 256, 0, stream>>>(Y, Ybf, sq, out);
    loss_kernel<<<(N / TILE) * (N / TILE), 256, 0, stream>>>(W, Ybf, sq, out);
}